// Round 14
// baseline (330.990 us; speedup 1.0000x reference)
//
#include <hip/hip_runtime.h>
#include <hip/hip_bf16.h>

#define CDIM 32
#define KCODES 4096
#define NROWS 65536
#define HW 4096
#define TPB 256
#define RPT 4                 // rows per thread
#define BETA 0.25f

// ---- workspace layout (bytes) ----
#define LOSS_OFF  0u
#define BIAS_OFF  256u
#define SCORE_OFF (BIAS_OFF + KCODES * 4u)
// scores: [kp][NROWS] floats, then idxs: [kp][NROWS] ints (offset depends on runtime KP)

// bias[k] = -0.5 * ||e_k||^2
__global__ __launch_bounds__(256) void vq_bias(const float* __restrict__ table,
                                               float* __restrict__ bias) {
    int k = blockIdx.x * 256 + threadIdx.x;
    if (k >= KCODES) return;
    const float4* row = (const float4*)(table + (size_t)k * CDIM);
    float s = 0.f;
#pragma unroll
    for (int i = 0; i < CDIM / 4; ++i) {
        float4 v = row[i];
        s = fmaf(v.x, v.x, s);
        s = fmaf(v.y, v.y, s);
        s = fmaf(v.z, v.z, s);
        s = fmaf(v.w, v.w, s);
    }
    bias[k] = -0.5f * s;
}

// Scalar-operand scoring, 4 rows/thread: e-rows + bias through the scalar pipe
// (wave-uniform s_load), z in VGPRs. 128 FMA-inst (256 cyc) of compute per
// 132 B of SMEM fetch; unroll-4 lets the compiler pipeline several e-rows.
__global__ __launch_bounds__(TPB, 3) void vq_main(const float* __restrict__ z,
                                                  const float* __restrict__ table,
                                                  const float* __restrict__ bias,
                                                  float* __restrict__ scores,
                                                  int* __restrict__ idxs,
                                                  int kslice) {
    const int t    = threadIdx.x;
    const int kp   = blockIdx.y;
    const int row0 = blockIdx.x * (TPB * RPT);   // 1024 rows/block, within one batch image
    const int n0   = row0 + t * RPT;             // rows n0..n0+3
    const int b    = n0 >> 12;
    const int hw   = n0 & (HW - 1);              // multiple of 4 -> float4-safe
    const float* zb = z + (size_t)b * CDIM * HW + hw;

    // 4 z-rows in registers (128 VGPR), coalesced float4 loads
    float z0[CDIM], z1[CDIM], z2[CDIM], z3[CDIM];
#pragma unroll
    for (int c = 0; c < CDIM; ++c) {
        float4 v = *(const float4*)(zb + (size_t)c * HW);
        z0[c] = v.x; z1[c] = v.y; z2[c] = v.z; z3[c] = v.w;
    }

    float best0 = -1e30f, best1 = -1e30f, best2 = -1e30f, best3 = -1e30f;
    int bi0 = 0, bi1 = 0, bi2 = 0, bi3 = 0;

    const int kbeg = kp * kslice;
    const int kend = kbeg + kslice;
#pragma unroll 4
    for (int k = kbeg; k < kend; ++k) {
        const float* er = table + (size_t)k * CDIM;   // uniform -> s_load_dwordx16 x2
        float bk = bias[k];                           // uniform -> s_load
        float a0 = bk, a1 = bk, a2 = bk, a3 = bk;
#pragma unroll
        for (int c = 0; c < CDIM; ++c) {
            float e = er[c];                          // SGPR operand
            a0 = fmaf(z0[c], e, a0);
            a1 = fmaf(z1[c], e, a1);
            a2 = fmaf(z2[c], e, a2);
            a3 = fmaf(z3[c], e, a3);
        }
        if (a0 > best0) { best0 = a0; bi0 = k; }      // strict >: first (lowest k) wins
        if (a1 > best1) { best1 = a1; bi1 = k; }
        if (a2 > best2) { best2 = a2; bi2 = k; }
        if (a3 > best3) { best3 = a3; bi3 = k; }
    }

    float* sp = scores + (size_t)kp * NROWS + n0;
    int*   ip = idxs   + (size_t)kp * NROWS + n0;
    *(float4*)sp = make_float4(best0, best1, best2, best3);
    *(int4*)ip   = make_int4(bi0, bi1, bi2, bi3);
}

__global__ __launch_bounds__(256) void vq_combine(const float* __restrict__ scores,
                                                  const int* __restrict__ idxs,
                                                  const float* __restrict__ z,
                                                  const float* __restrict__ table,
                                                  float* __restrict__ out_zq,
                                                  float* __restrict__ out_idx,
                                                  float* __restrict__ loss,
                                                  int kp_count) {
    const int n = blockIdx.x * 256 + threadIdx.x;
    float best = -1e30f;
    int bi = 0;
    for (int kp = 0; kp < kp_count; ++kp) {   // ascending partitions => lowest k wins ties
        float s = scores[(size_t)kp * NROWS + n];
        int   i = idxs[(size_t)kp * NROWS + n];
        if (s > best) { best = s; bi = i; }
    }

    const int b  = n >> 12;
    const int hw = n & (HW - 1);

    const float* zbp = z + (size_t)b * CDIM * HW + hw;
    float z2 = 0.f;
#pragma unroll
    for (int c = 0; c < CDIM; ++c) {
        float v = zbp[(size_t)c * HW];
        z2 = fmaf(v, v, z2);
    }

    out_idx[n] = (float)bi;

    const float4* trow = (const float4*)(table + (size_t)bi * CDIM);
    float* o = out_zq + (size_t)b * CDIM * HW + hw;
#pragma unroll
    for (int c4 = 0; c4 < CDIM / 4; ++c4) {
        float4 v = trow[c4];
        o[(size_t)(c4 * 4 + 0) * HW] = v.x;
        o[(size_t)(c4 * 4 + 1) * HW] = v.y;
        o[(size_t)(c4 * 4 + 2) * HW] = v.z;
        o[(size_t)(c4 * 4 + 3) * HW] = v.w;
    }

    // d = ||z||^2 - 2*(z.e - 0.5||e||^2) = ||z - e||^2
    float d = fmaxf(z2 - 2.0f * best, 0.0f);
#pragma unroll
    for (int off = 32; off; off >>= 1) d += __shfl_down(d, off);
    if ((threadIdx.x & 63) == 0) atomicAdd(loss, d);
}

__global__ void vq_finalize(const float* __restrict__ loss,
                            float* __restrict__ out_loss) {
    out_loss[0] = loss[0] * (1.0f + BETA) / (float)((size_t)NROWS * CDIM);
}

extern "C" void kernel_launch(void* const* d_in, const int* in_sizes, int n_in,
                              void* d_out, int out_size, void* d_ws, size_t ws_size,
                              hipStream_t stream) {
    const float* z     = (const float*)d_in[0];
    const float* table = (const float*)d_in[1];

    // Runtime KP selection (deterministic per ws_size -> graph-safe).
    const size_t need16 = (size_t)SCORE_OFF + 16ull * NROWS * 8ull;
    const int kp_count  = (ws_size >= need16) ? 16 : 8;
    const int kslice    = KCODES / kp_count;

    char* ws = (char*)d_ws;
    float* loss   = (float*)(ws + LOSS_OFF);
    float* bias   = (float*)(ws + BIAS_OFF);
    float* scores = (float*)(ws + SCORE_OFF);
    int*   idxs   = (int*)(ws + SCORE_OFF + (size_t)kp_count * NROWS * 4u);

    float* out_zq   = (float*)d_out;
    float* out_idx  = out_zq + (size_t)NROWS * CDIM;
    float* out_loss = out_idx + NROWS;

    hipMemsetAsync(loss, 0, sizeof(float), stream);

    vq_bias<<<KCODES / 256, 256, 0, stream>>>(table, bias);

    dim3 grid(NROWS / (TPB * RPT), kp_count);   // 64 x 16 = 1024 blocks -> 4 blocks/CU
    vq_main<<<grid, TPB, 0, stream>>>(z, table, bias, scores, idxs, kslice);

    vq_combine<<<NROWS / 256, 256, 0, stream>>>(scores, idxs, z, table,
                                                out_zq, out_idx, loss, kp_count);
    vq_finalize<<<1, 1, 0, stream>>>(loss, out_loss);
}

// Round 16
// 292.943 us; speedup vs baseline: 1.1299x; 1.1299x over previous
//
#include <hip/hip_runtime.h>
#include <hip/hip_bf16.h>

#define CDIM 32
#define KCODES 4096
#define NROWS 65536
#define HW 4096
#define KP 8
#define KSLICE (KCODES / KP)   // 512 codes per partition
#define TPB 256
#define BETA 0.25f

// ---- workspace layout (bytes) ---- (max 4.2 MB, proven to fit)
#define LOSS_OFF  0u
#define BIAS_OFF  256u
#define SCORE_OFF (BIAS_OFF + KCODES * 4u)
#define IDX_OFF   (SCORE_OFF + (unsigned)KP * NROWS * 4u)

// bias[k] = -0.5 * ||e_k||^2
__global__ __launch_bounds__(256) void vq_bias(const float* __restrict__ table,
                                               float* __restrict__ bias) {
    int k = blockIdx.x * 256 + threadIdx.x;
    if (k >= KCODES) return;
    const float4* row = (const float4*)(table + (size_t)k * CDIM);
    float s = 0.f;
#pragma unroll
    for (int i = 0; i < CDIM / 4; ++i) {
        float4 v = row[i];
        s = fmaf(v.x, v.x, s);
        s = fmaf(v.y, v.y, s);
        s = fmaf(v.z, v.z, s);
        s = fmaf(v.w, v.w, s);
    }
    bias[k] = -0.5f * s;
}

// Scalar-operand scoring: e-rows + bias through the scalar pipe (wave-uniform
// s_load -> SGPR operand), z rows PINNED in VGPRs via opaque asm (the compiler
// otherwise rematerializes the z loads inside the K-loop -> L1-BW bound, the
// ~100us stall seen in rounds 2-14).
__global__ __launch_bounds__(TPB, 2) void vq_main(const float* __restrict__ z,
                                                  const float* __restrict__ table,
                                                  const float* __restrict__ bias,
                                                  float* __restrict__ scores,
                                                  int* __restrict__ idxs) {
    const int t    = threadIdx.x;
    const int kp   = blockIdx.y;
    const int row0 = blockIdx.x * (TPB * 2);
    const int n0   = row0 + t * 2;          // rows n0, n0+1
    const int b    = n0 >> 12;
    const int hw   = n0 & (HW - 1);
    const float* zb = z + (size_t)b * CDIM * HW + hw;

    // 2 z-rows in registers (64 VGPR), coalesced float2 loads, PINNED opaque.
    float z0[CDIM], z1[CDIM];
#pragma unroll
    for (int c = 0; c < CDIM; ++c) {
        float2 v = *(const float2*)(zb + (size_t)c * HW);
        z0[c] = v.x;
        z1[c] = v.y;
        asm volatile("" : "+v"(z0[c]), "+v"(z1[c]));  // forbid rematerialization
    }

    float best0 = -1e30f, best1 = -1e30f;
    int bi0 = 0, bi1 = 0;

    const int kbeg = kp * KSLICE;
    const int kend = kbeg + KSLICE;
#pragma unroll 2
    for (int k = kbeg; k < kend; ++k) {
        const float* er = table + (size_t)k * CDIM;   // uniform -> s_load_dwordx16 x2
        float a0 = bias[k];                           // uniform -> s_load
        float a1 = a0;
#pragma unroll
        for (int c = 0; c < CDIM; ++c) {
            float e = er[c];                          // SGPR operand
            a0 = fmaf(z0[c], e, a0);
            a1 = fmaf(z1[c], e, a1);
        }
        if (a0 > best0) { best0 = a0; bi0 = k; }      // strict >: first (lowest k) wins
        if (a1 > best1) { best1 = a1; bi1 = k; }
    }

    *(float2*)(scores + (size_t)kp * NROWS + n0) = make_float2(best0, best1);
    *(int2*)(idxs + (size_t)kp * NROWS + n0)     = make_int2(bi0, bi1);
}

__global__ __launch_bounds__(256) void vq_combine(const float* __restrict__ scores,
                                                  const int* __restrict__ idxs,
                                                  const float* __restrict__ z,
                                                  const float* __restrict__ table,
                                                  float* __restrict__ out_zq,
                                                  float* __restrict__ out_idx,
                                                  float* __restrict__ loss) {
    const int n = blockIdx.x * 256 + threadIdx.x;
    float best = -1e30f;
    int bi = 0;
#pragma unroll
    for (int kp = 0; kp < KP; ++kp) {   // ascending partitions => lowest k wins ties
        float s = scores[(size_t)kp * NROWS + n];
        int   i = idxs[(size_t)kp * NROWS + n];
        if (s > best) { best = s; bi = i; }
    }

    const int b  = n >> 12;
    const int hw = n & (HW - 1);

    const float* zbp = z + (size_t)b * CDIM * HW + hw;
    float z2 = 0.f;
#pragma unroll
    for (int c = 0; c < CDIM; ++c) {
        float v = zbp[(size_t)c * HW];
        z2 = fmaf(v, v, z2);
    }

    out_idx[n] = (float)bi;

    const float4* trow = (const float4*)(table + (size_t)bi * CDIM);
    float* o = out_zq + (size_t)b * CDIM * HW + hw;
#pragma unroll
    for (int c4 = 0; c4 < CDIM / 4; ++c4) {
        float4 v = trow[c4];
        o[(size_t)(c4 * 4 + 0) * HW] = v.x;
        o[(size_t)(c4 * 4 + 1) * HW] = v.y;
        o[(size_t)(c4 * 4 + 2) * HW] = v.z;
        o[(size_t)(c4 * 4 + 3) * HW] = v.w;
    }

    // d = ||z||^2 - 2*(z.e - 0.5||e||^2) = ||z - e||^2
    float d = fmaxf(z2 - 2.0f * best, 0.0f);
#pragma unroll
    for (int off = 32; off; off >>= 1) d += __shfl_down(d, off);
    if ((threadIdx.x & 63) == 0) atomicAdd(loss, d);
}

__global__ void vq_finalize(const float* __restrict__ loss,
                            float* __restrict__ out_loss) {
    out_loss[0] = loss[0] * (1.0f + BETA) / (float)((size_t)NROWS * CDIM);
}

extern "C" void kernel_launch(void* const* d_in, const int* in_sizes, int n_in,
                              void* d_out, int out_size, void* d_ws, size_t ws_size,
                              hipStream_t stream) {
    const float* z     = (const float*)d_in[0];
    const float* table = (const float*)d_in[1];

    char* ws = (char*)d_ws;
    float* loss   = (float*)(ws + LOSS_OFF);
    float* bias   = (float*)(ws + BIAS_OFF);
    float* scores = (float*)(ws + SCORE_OFF);
    int*   idxs   = (int*)(ws + IDX_OFF);

    float* out_zq   = (float*)d_out;
    float* out_idx  = out_zq + (size_t)NROWS * CDIM;
    float* out_loss = out_idx + NROWS;

    hipMemsetAsync(loss, 0, sizeof(float), stream);

    vq_bias<<<KCODES / 256, 256, 0, stream>>>(table, bias);

    dim3 grid(NROWS / (TPB * 2), KP);   // 128 x 8 = 1024 blocks, 4 waves each
    vq_main<<<grid, TPB, 0, stream>>>(z, table, bias, scores, idxs);

    vq_combine<<<NROWS / 256, 256, 0, stream>>>(scores, idxs, z, table,
                                                out_zq, out_idx, loss);
    vq_finalize<<<1, 1, 0, stream>>>(loss, out_loss);
}